// Round 5
// baseline (16033.568 us; speedup 1.0000x reference)
//
#include <hip/hip_runtime.h>
#include <hip/hip_bf16.h>

typedef float f32x4 __attribute__((ext_vector_type(4)));
typedef __bf16 bf16x8 __attribute__((ext_vector_type(8)));

#define WREC 1544              // ushorts per (gate,col) record: 1536 data + 8 pad (772 dw, %32=4 -> conflict-free)
#define PBASE 148224           // byte offset of partial buffer in smem (48*WREC*2)
#define SMEM_BYTES 163584      // 148224 + 12*320*4 = 163584 <= 163840

__device__ __forceinline__ unsigned short f2b(float f) {
  unsigned u = __builtin_bit_cast(unsigned, f);
  unsigned r = (u + 0x7fffu + ((u >> 16) & 1u)) >> 16;   // RNE
  return (unsigned short)r;
}

__device__ __forceinline__ bf16x8 pack8(float4 a, float4 b) {
  union { __hip_bfloat162 h2[4]; bf16x8 v; } u;
  u.h2[0] = __float22bfloat162_rn(make_float2(a.x, a.y));
  u.h2[1] = __float22bfloat162_rn(make_float2(a.z, a.w));
  u.h2[2] = __float22bfloat162_rn(make_float2(b.x, b.y));
  u.h2[3] = __float22bfloat162_rn(make_float2(b.z, b.w));
  return u.v;
}

// ---------------- transpose fp32 [R][C] -> bf16 [C][R] ----------------
__global__ __launch_bounds__(256) void tconv(const float* __restrict__ in,
                                             unsigned short* __restrict__ out,
                                             int R, int C) {
  __shared__ unsigned short tile[32][33];
  const int tx = threadIdx.x & 31, ty = threadIdx.x >> 5;
  const int c0 = blockIdx.x * 32, r0 = blockIdx.y * 32;
#pragma unroll
  for (int p = 0; p < 4; ++p) {
    int r = ty + p * 8;
    tile[r][tx] = f2b(in[(size_t)(r0 + r) * C + c0 + tx]);
  }
  __syncthreads();
#pragma unroll
  for (int p = 0; p < 4; ++p) {
    int cc = ty + p * 8;
    out[(size_t)(c0 + cc) * R + r0 + tx] = tile[tx][cc];
  }
}

// ---------------- combined bias: [4][1024] = bz, br, bhi, bhr ----------
__global__ __launch_bounds__(256) void bprep(const float* __restrict__ bias,
                                             float* __restrict__ bc) {
  const int u = blockIdx.x * 256 + threadIdx.x;  // 0..1023
  bc[u]        = bias[u]        + bias[3072 + u];
  bc[1024 + u] = bias[1024 + u] + bias[4096 + u];
  bc[2048 + u] = bias[2048 + u];
  bc[3072 + u] = bias[5120 + u];
}

// ---------------- zero init: hbf0 + barrier counters -------------------
__global__ __launch_bounds__(256) void zinit(uint4* __restrict__ hbf0,
                                             unsigned int* __restrict__ bar) {
  const int id = blockIdx.x * 256 + threadIdx.x;   // 32768 uint4 = 512 KB
  hbf0[id] = make_uint4(0u, 0u, 0u, 0u);
  if (id < 512) bar[id] = 0u;
}

// ---------------- persistent GRU scan ----------------------------------
// 256 blocks (1/CU) x 512 thr (8 waves). Block = (cg, rgc): 16 u-cols, 64
// rows. Weights (16 cols x 3 gates x K=1536 bf16) staged ONCE into LDS
// (fence-immune; rounds 3/4 showed agent fences force re-load of global-
// sourced registers). 8 waves = 4 rowgroups x 2 K-halves:
//   kh0: x-K 0..511 (16 ksteps) + h-K 0..255 (8)   -> acc z,r,xh,rh + epilogue
//   kh1: h-K 256..1023 (24 ksteps)                 -> acc z,r,rh -> LDS partials
// Device sync: 4 independent per-rowgroup barriers (64 blocks each).
__global__ __launch_bounds__(512, 2) void gru_persist(
    const float* __restrict__ x,             // fp32 [256][256][512]
    const unsigned short* __restrict__ Wt,   // bf16 [3072][512]
    const unsigned short* __restrict__ Ut,   // bf16 [3072][1024]
    const float* __restrict__ biasC,         // [4][1024]
    unsigned short* __restrict__ hA,         // bf16 [256][1024]
    unsigned short* __restrict__ hB,
    float* __restrict__ out,                 // fp32 [256][1024]
    unsigned int* __restrict__ bar)          // 4 counters, 512 B apart
{
  extern __shared__ char smem[];
  unsigned short* wl = (unsigned short*)smem;
  float* pbuf = (float*)(smem + PBASE);

  const int tid = threadIdx.x;
  const int lane = tid & 63;
  const int w = tid >> 6;                 // 0..7
  const int rg = w & 3;                   // rowgroup within block
  const int kh = w >> 2;                  // K-half
  const int cg = (int)blockIdx.x >> 2;    // 0..63 u-col group
  const int rgc = (int)blockIdx.x & 3;    // row-group of this block
  const int r0 = rgc << 6;
  const int u16l = lane & 15, kq = lane >> 4;

  // ---- stage weights into LDS: 48 records x 192 uint4 (once) ----
  for (int idx = tid; idx < 48 * 192; idx += 512) {
    const int rec = idx / 192, c = idx - rec * 192;
    const int col = rec & 15, gate = rec >> 4;
    uint4 v;
    if (c < 64)
      v = *(const uint4*)&Wt[(size_t)(gate * 1024 + cg * 16 + col) * 512 + c * 8];
    else
      v = *(const uint4*)&Ut[(size_t)(gate * 1024 + cg * 16 + col) * 1024 + (size_t)(c - 64) * 8];
    *(uint4*)&wl[(size_t)rec * WREC + c * 8] = v;
  }
  __syncthreads();

  const int cu = cg * 16 + u16l;
  const float bz = biasC[cu], br = biasC[1024 + cu];
  const float bhi = biasC[2048 + cu], bhr = biasC[3072 + cu];

  const unsigned short* wrec = wl + (size_t)u16l * WREC + kq * 8;  // + gate*16*WREC + k
  const int arow = r0 + rg * 16 + u16l;
  const float* xrow = x + (size_t)arow * 131072 + kq * 8;
  f32x4 hst = {0.f, 0.f, 0.f, 0.f};       // fp32 h state (kh0 waves)
  unsigned int tgt = 0;

  for (int t = 0; t < 256; ++t) {
    const unsigned short* hin = (t & 1) ? hB : hA;
    unsigned short* hout = (t & 1) ? hA : hB;
    const unsigned short* hrow = hin + (size_t)arow * 1024 + kq * 8;

    f32x4 az = {0.f,0.f,0.f,0.f}, ar = az, ah0 = az, ah1 = az;

    if (kh == 0) {
      const float* xp = xrow + t * 512;
#pragma unroll
      for (int i = 0; i < 16; ++i) {          // x-part: K 0..511
        float4 a0 = *(const float4*)(xp + i * 32);
        float4 a1 = *(const float4*)(xp + i * 32 + 4);
        bf16x8 af = pack8(a0, a1);
        bf16x8 b0 = *(const bf16x8*)(wrec + i * 32);
        bf16x8 b1 = *(const bf16x8*)(wrec + 16 * WREC + i * 32);
        bf16x8 b2 = *(const bf16x8*)(wrec + 32 * WREC + i * 32);
        az  = __builtin_amdgcn_mfma_f32_16x16x32_bf16(af, b0, az, 0, 0, 0);
        ar  = __builtin_amdgcn_mfma_f32_16x16x32_bf16(af, b1, ar, 0, 0, 0);
        ah0 = __builtin_amdgcn_mfma_f32_16x16x32_bf16(af, b2, ah0, 0, 0, 0);
      }
#pragma unroll
      for (int j = 0; j < 8; ++j) {           // h-part: h-K 0..255 (gk 512..767)
        bf16x8 af = *(const bf16x8*)(hrow + j * 32);
        bf16x8 b0 = *(const bf16x8*)(wrec + 512 + j * 32);
        bf16x8 b1 = *(const bf16x8*)(wrec + 16 * WREC + 512 + j * 32);
        bf16x8 b2 = *(const bf16x8*)(wrec + 32 * WREC + 512 + j * 32);
        az  = __builtin_amdgcn_mfma_f32_16x16x32_bf16(af, b0, az, 0, 0, 0);
        ar  = __builtin_amdgcn_mfma_f32_16x16x32_bf16(af, b1, ar, 0, 0, 0);
        ah1 = __builtin_amdgcn_mfma_f32_16x16x32_bf16(af, b2, ah1, 0, 0, 0);
      }
    } else {
#pragma unroll
      for (int i = 0; i < 24; ++i) {          // h-part: h-K 256..1023 (gk 768..1535)
        bf16x8 af = *(const bf16x8*)(hrow + 256 + i * 32);
        bf16x8 b0 = *(const bf16x8*)(wrec + 768 + i * 32);
        bf16x8 b1 = *(const bf16x8*)(wrec + 16 * WREC + 768 + i * 32);
        bf16x8 b2 = *(const bf16x8*)(wrec + 32 * WREC + 768 + i * 32);
        az  = __builtin_amdgcn_mfma_f32_16x16x32_bf16(af, b0, az, 0, 0, 0);
        ar  = __builtin_amdgcn_mfma_f32_16x16x32_bf16(af, b1, ar, 0, 0, 0);
        ah1 = __builtin_amdgcn_mfma_f32_16x16x32_bf16(af, b2, ah1, 0, 0, 0);
      }
      // write partials: 3 tiles per rg, [col][row] pitch 20 (2-way banks, free)
      float* pb = pbuf + rg * 3 * 320;
      const int po = u16l * 20 + kq * 4;
      *(f32x4*)&pb[po]       = az;
      *(f32x4*)&pb[320 + po] = ar;
      *(f32x4*)&pb[640 + po] = ah1;
    }
    __syncthreads();

    if (kh == 0) {
      // reduce + gates + state update (C-layout: col=lane&15, row=kq*4+v)
      float* pb = pbuf + rg * 3 * 320;
      const int po = u16l * 20 + kq * 4;
      f32x4 pz = *(const f32x4*)&pb[po];
      f32x4 pr = *(const f32x4*)&pb[320 + po];
      f32x4 ph = *(const f32x4*)&pb[640 + po];
      f32x4 hnew;
#pragma unroll
      for (int v = 0; v < 4; ++v) {
        const float z  = 1.f / (1.f + __expf(-(az[v] + pz[v] + bz)));
        const float rr = 1.f / (1.f + __expf(-(ar[v] + pr[v] + br)));
        const float hp = ah0[v] + bhi + rr * (ah1[v] + ph[v] + bhr);
        const float e2 = __expf(2.f * hp);
        const float hh = 1.f - 2.f / (e2 + 1.f);
        hnew[v] = hh + z * (hst[v] - hh);
      }
      hst = hnew;
      if (t < 255) {
#pragma unroll
        for (int v = 0; v < 4; ++v)
          hout[(size_t)(r0 + rg * 16 + kq * 4 + v) * 1024 + cu] = f2b(hnew[v]);
      } else {
#pragma unroll
        for (int v = 0; v < 4; ++v)
          out[(size_t)(r0 + rg * 16 + kq * 4 + v) * 1024 + cu] = hnew[v];
      }
    }

    if (t < 255) {
      // ---- per-rowgroup device barrier (64 blocks) ----
      __syncthreads();
      __threadfence();
      if (tid == 0) {
        __hip_atomic_fetch_add(&bar[rgc * 128], 1u, __ATOMIC_RELEASE, __HIP_MEMORY_SCOPE_AGENT);
        tgt += 64;
        while (__hip_atomic_load(&bar[rgc * 128], __ATOMIC_RELAXED, __HIP_MEMORY_SCOPE_AGENT) < tgt)
          __builtin_amdgcn_s_sleep(1);
      }
      __syncthreads();
      __builtin_amdgcn_fence(__ATOMIC_ACQUIRE, "agent");
    }
  }
}

extern "C" void kernel_launch(void* const* d_in, const int* in_sizes, int n_in,
                              void* d_out, int out_size, void* d_ws, size_t ws_size,
                              hipStream_t stream) {
  (void)in_sizes; (void)n_in; (void)out_size; (void)ws_size;
  const float* x    = (const float*)d_in[0];   // (256,256,512)
  const float* Wk   = (const float*)d_in[1];   // (512,3072)
  const float* Rk   = (const float*)d_in[2];   // (1024,3072)
  const float* bias = (const float*)d_in[3];   // (2,3072)
  float* out = (float*)d_out;

  char* ws = (char*)d_ws;
  unsigned short* Wt    = (unsigned short*)(ws + 0);          // 3,145,728 B
  unsigned short* Ut    = (unsigned short*)(ws + 3145728);    // 6,291,456 B
  float*          biasC = (float*)(ws + 9437184);             // 16,384 B
  unsigned short* hbf0  = (unsigned short*)(ws + 9453568);    // 524,288 B
  unsigned short* hbf1  = (unsigned short*)(ws + 9977856);    // 524,288 B
  unsigned int*   bar   = (unsigned int*)(ws + 10502144);     // 2,048 B

  static int smem_set = 0;
  (void)smem_set;
  hipFuncSetAttribute((const void*)gru_persist,
                      hipFuncAttributeMaxDynamicSharedMemorySize, SMEM_BYTES);

  tconv<<<dim3(96, 16), 256, 0, stream>>>(Wk, Wt, 512, 3072);
  tconv<<<dim3(96, 32), 256, 0, stream>>>(Rk, Ut, 1024, 3072);
  bprep<<<4, 256, 0, stream>>>(bias, biasC);
  zinit<<<128, 256, 0, stream>>>((uint4*)hbf0, bar);

  gru_persist<<<256, 512, SMEM_BYTES, stream>>>(x, Wt, Ut, biasC, hbf0, hbf1, out, bar);
}